// Round 5
// baseline (372.670 us; speedup 1.0000x reference)
//
#include <hip/hip_runtime.h>

// Problem constants (from reference)
#define MM   6
#define BB   128
#define TT   32
#define DIN  64
#define HH   512
#define EE   512
#define NEMB 32
#define XP   72    // padded x row (bf16 elems): 144 B row stride -> uniform banks, 16B-aligned
#define HP   520   // padded h row (bf16 elems): 1040 B row stride -> uniform banks, 16B-aligned

typedef __attribute__((ext_vector_type(8))) short bf16x8;   // MFMA A/B frag (4 VGPR)
typedef __attribute__((ext_vector_type(4))) float f32x4;    // MFMA C/D frag

// bf16 round-to-nearest-even split helpers (bit ops; no HIP bf16 API quirks)
static __device__ __forceinline__ unsigned short f2bf(float f) {
    unsigned int u = __float_as_uint(f);
    u += 0x7FFFu + ((u >> 16) & 1u);
    return (unsigned short)(u >> 16);
}
static __device__ __forceinline__ float bf2f(unsigned short h) {
    return __uint_as_float(((unsigned int)h) << 16);
}

// Fragment layouts (HW-verified trio, learn_hip m89/m92):
//   A (16x32): lane l, elem i -> A[l&15][(l>>4)*8 + i]
//   B (32x16): lane l, elem i -> B[(l>>4)*8 + i][l&15]
//   D (16x16): lane l, reg  r -> D[(l>>4)*4 + r][l&15]
// 3-term split: x*w ~= xh*wh + xh*wl + xl*wh  (rel err ~2^-17)

__global__ __launch_bounds__(256, 2) void tok_mfma(
    const float* __restrict__ state,   // (B, T, M*DIN)
    const int*   __restrict__ emb_ids, // (B)
    const float* __restrict__ W1,      // (M, NEMB, DIN, H)
    const float* __restrict__ b1,      // (M, NEMB, H)
    const float* __restrict__ W2,      // (M, NEMB, H, E)
    const float* __restrict__ b2,      // (M, NEMB, E)
    const float* __restrict__ te,      // (M, E)
    float* __restrict__ out)           // (B, M*T, E)
{
    __shared__ __align__(16) unsigned short x_hi[TT][XP];
    __shared__ __align__(16) unsigned short x_lo[TT][XP];
    __shared__ __align__(16) unsigned short h_hi[TT][HP];
    __shared__ __align__(16) unsigned short h_lo[TT][HP];

    const int tid  = threadIdx.x;
    const int lane = tid & 63;
    const int w    = tid >> 6;      // wave 0..3: owns output cols [w*128, w*128+128)
    const int lr   = lane & 15;
    const int lg   = lane >> 4;

    const int bm = blockIdx.x;
    const int m  = bm % MM;
    const int b  = bm / MM;
    const int id = emb_ids[b];

    const float* xg  = state + (size_t)b * TT * (MM * DIN) + m * DIN;
    const float* W1p = W1 + (size_t)(m * NEMB + id) * DIN * HH;
    const float* b1p = b1 + (size_t)(m * NEMB + id) * HH;
    const float* W2p = W2 + (size_t)(m * NEMB + id) * HH * EE;
    const float* b2p = b2 + (size_t)(m * NEMB + id) * EE;
    const float* tep = te + m * EE;

    // ---- stage x (32x64 fp32) as bf16 hi/lo in LDS ----
    #pragma unroll
    for (int k = 0; k < 2; ++k) {
        int f  = k * 256 + tid;        // 0..511 float4 slots
        int t  = f >> 4;               // token row
        int i4 = f & 15;               // float4 within row
        float4 v = *reinterpret_cast<const float4*>(xg + (size_t)t * (MM * DIN) + i4 * 4);
        ushort4 hi, lo;
        hi.x = f2bf(v.x); lo.x = f2bf(v.x - bf2f(hi.x));
        hi.y = f2bf(v.y); lo.y = f2bf(v.y - bf2f(hi.y));
        hi.z = f2bf(v.z); lo.z = f2bf(v.z - bf2f(hi.z));
        hi.w = f2bf(v.w); lo.w = f2bf(v.w - bf2f(hi.w));
        *reinterpret_cast<ushort4*>(&x_hi[t][i4 * 4]) = hi;
        *reinterpret_cast<ushort4*>(&x_lo[t][i4 * 4]) = lo;
    }
    __syncthreads();

    // ---- layer 1: h = relu(x @ W1 + b1), wave w computes cols [w*128, w*128+128) ----
    bf16x8 xa_h[2][2], xa_l[2][2];   // [row-tile][k-step]
    #pragma unroll
    for (int r0 = 0; r0 < 2; ++r0)
        #pragma unroll
        for (int kk = 0; kk < 2; ++kk) {
            xa_h[r0][kk] = *reinterpret_cast<const bf16x8*>(&x_hi[r0 * 16 + lr][kk * 32 + lg * 8]);
            xa_l[r0][kk] = *reinterpret_cast<const bf16x8*>(&x_lo[r0 * 16 + lr][kk * 32 + lg * 8]);
        }

    #pragma unroll
    for (int j = 0; j < 8; ++j) {
        const int n = w * 128 + j * 16 + lr;
        float bv = b1p[n];
        f32x4 a0 = {bv, bv, bv, bv};
        f32x4 a1 = {bv, bv, bv, bv};
        #pragma unroll
        for (int kk = 0; kk < 2; ++kk) {
            // B-frag streamed from global W1: row k = kk*32 + lg*8 + i, col n
            const float* wp = W1p + (size_t)(kk * 32 + lg * 8) * HH + n;
            bf16x8 bh, bl;
            #pragma unroll
            for (int i = 0; i < 8; ++i) {
                float wv = wp[(size_t)i * HH];
                unsigned short h_ = f2bf(wv);
                bh[i] = (short)h_;
                bl[i] = (short)f2bf(wv - bf2f(h_));
            }
            a0 = __builtin_amdgcn_mfma_f32_16x16x32_bf16(xa_h[0][kk], bh, a0, 0, 0, 0);
            a0 = __builtin_amdgcn_mfma_f32_16x16x32_bf16(xa_h[0][kk], bl, a0, 0, 0, 0);
            a0 = __builtin_amdgcn_mfma_f32_16x16x32_bf16(xa_l[0][kk], bh, a0, 0, 0, 0);
            a1 = __builtin_amdgcn_mfma_f32_16x16x32_bf16(xa_h[1][kk], bh, a1, 0, 0, 0);
            a1 = __builtin_amdgcn_mfma_f32_16x16x32_bf16(xa_h[1][kk], bl, a1, 0, 0, 0);
            a1 = __builtin_amdgcn_mfma_f32_16x16x32_bf16(xa_l[1][kk], bh, a1, 0, 0, 0);
        }
        // relu + hi/lo split -> h LDS (D: row = r0*16 + lg*4 + r, col = n)
        #pragma unroll
        for (int r = 0; r < 4; ++r) {
            float h0 = fmaxf(a0[r], 0.0f);
            unsigned short hh0 = f2bf(h0);
            h_hi[lg * 4 + r][n] = hh0;
            h_lo[lg * 4 + r][n] = f2bf(h0 - bf2f(hh0));
            float h1 = fmaxf(a1[r], 0.0f);
            unsigned short hh1 = f2bf(h1);
            h_hi[16 + lg * 4 + r][n] = hh1;
            h_lo[16 + lg * 4 + r][n] = f2bf(h1 - bf2f(hh1));
        }
    }
    __syncthreads();

    // ---- layer 2: z = h @ W2 + b2 + te ----
    float bias2[8];
    #pragma unroll
    for (int j = 0; j < 8; ++j) {
        int n = w * 128 + j * 16 + lr;
        bias2[j] = b2p[n] + tep[n];
    }
    f32x4 acc[2][8];
    #pragma unroll
    for (int r0 = 0; r0 < 2; ++r0)
        #pragma unroll
        for (int j = 0; j < 8; ++j) {
            f32x4 t0 = {bias2[j], bias2[j], bias2[j], bias2[j]};
            acc[r0][j] = t0;
        }

    for (int kk = 0; kk < 16; ++kk) {
        // A-frags (h) for both row-tiles, hi and lo
        bf16x8 ah0 = *reinterpret_cast<const bf16x8*>(&h_hi[lr][kk * 32 + lg * 8]);
        bf16x8 al0 = *reinterpret_cast<const bf16x8*>(&h_lo[lr][kk * 32 + lg * 8]);
        bf16x8 ah1 = *reinterpret_cast<const bf16x8*>(&h_hi[16 + lr][kk * 32 + lg * 8]);
        bf16x8 al1 = *reinterpret_cast<const bf16x8*>(&h_lo[16 + lr][kk * 32 + lg * 8]);
        #pragma unroll
        for (int j = 0; j < 8; ++j) {
            const float* wp = W2p + (size_t)(kk * 32 + lg * 8) * EE + (w * 128 + j * 16 + lr);
            bf16x8 bh, bl;
            #pragma unroll
            for (int i = 0; i < 8; ++i) {
                float wv = wp[(size_t)i * EE];
                unsigned short h_ = f2bf(wv);
                bh[i] = (short)h_;
                bl[i] = (short)f2bf(wv - bf2f(h_));
            }
            acc[0][j] = __builtin_amdgcn_mfma_f32_16x16x32_bf16(ah0, bh, acc[0][j], 0, 0, 0);
            acc[0][j] = __builtin_amdgcn_mfma_f32_16x16x32_bf16(ah0, bl, acc[0][j], 0, 0, 0);
            acc[0][j] = __builtin_amdgcn_mfma_f32_16x16x32_bf16(al0, bh, acc[0][j], 0, 0, 0);
            acc[1][j] = __builtin_amdgcn_mfma_f32_16x16x32_bf16(ah1, bh, acc[1][j], 0, 0, 0);
            acc[1][j] = __builtin_amdgcn_mfma_f32_16x16x32_bf16(ah1, bl, acc[1][j], 0, 0, 0);
            acc[1][j] = __builtin_amdgcn_mfma_f32_16x16x32_bf16(al1, bh, acc[1][j], 0, 0, 0);
        }
    }

    // ---- epilogue: out[b, m*T + row, n] ----
    float* outp = out + ((size_t)(b * MM + m) * TT) * EE;
    #pragma unroll
    for (int r0 = 0; r0 < 2; ++r0)
        #pragma unroll
        for (int j = 0; j < 8; ++j) {
            int n = w * 128 + j * 16 + lr;
            #pragma unroll
            for (int r = 0; r < 4; ++r) {
                int row = r0 * 16 + lg * 4 + r;
                outp[(size_t)row * EE + n] = acc[r0][j][r];
            }
        }
}

extern "C" void kernel_launch(void* const* d_in, const int* in_sizes, int n_in,
                              void* d_out, int out_size, void* d_ws, size_t ws_size,
                              hipStream_t stream) {
    const float* state   = (const float*)d_in[0];
    const int*   emb_ids = (const int*)d_in[1];
    const float* W1      = (const float*)d_in[2];
    const float* b1      = (const float*)d_in[3];
    const float* W2      = (const float*)d_in[4];
    const float* b2      = (const float*)d_in[5];
    const float* te      = (const float*)d_in[6];
    float*       out     = (float*)d_out;

    dim3 grid(BB * MM);
    dim3 block(256);
    tok_mfma<<<grid, block, 0, stream>>>(state, emb_ids, W1, b1, W2, b2, te, out);
}